// Round 12
// baseline (243.966 us; speedup 1.0000x reference)
//
#include <hip/hip_runtime.h>
#include <hip/hip_bf16.h>
#include <cstdint>
#include <cstddef>

typedef __hip_bfloat16 bf16;
typedef short short8 __attribute__((ext_vector_type(8)));
typedef float f32x4 __attribute__((ext_vector_type(4)));

#define S_LEN 2048
#define DMODEL 2048
#define NQKV 6144
#define NHEADS 32
#define HDIM 64
// log2(10000)/32
#define ROPE_L2 0.4152410118609203f
// 0.125 * log2(e): folded into Q so attn softmax runs in exp2 domain
#define Q_PRESCALE 0.18033688011112042f

__device__ __forceinline__ void async_copy16(const bf16* g, bf16* l) {
  __builtin_amdgcn_global_load_lds(
      (const __attribute__((address_space(1))) void*)g,
      (__attribute__((address_space(3))) void*)l, 16, 0, 0);
}

__device__ __forceinline__ f32x4 mfma_bf16(short8 a, short8 b, f32x4 c) {
  return __builtin_amdgcn_mfma_f32_16x16x32_bf16(a, b, c, 0, 0, 0);
}

// ---------------- fused fp32 -> bf16 convert of x, Wqkv, Wo ----------------
__global__ __launch_bounds__(256) void cvt3_kernel(const float* __restrict__ sx,
                                                   bf16* __restrict__ dx,
                                                   const float* __restrict__ sw,
                                                   bf16* __restrict__ dw,
                                                   const float* __restrict__ so,
                                                   bf16* __restrict__ dov) {
  int i = blockIdx.x * 256 + threadIdx.x;
  const float* s;
  bf16* d;
  if (i < 1048576) {
    s = sx; d = dx;
  } else if (i < 4194304) {
    s = sw; d = dw; i -= 1048576;
  } else {
    s = so; d = dov; i -= 4194304;
  }
  const float4 v = ((const float4*)s)[i];
  union { bf16 h[4]; ushort4 u; } tmp;
  tmp.h[0] = __float2bfloat16(v.x);
  tmp.h[1] = __float2bfloat16(v.y);
  tmp.h[2] = __float2bfloat16(v.z);
  tmp.h[3] = __float2bfloat16(v.w);
  ((ushort4*)d)[i] = tmp.u;
}

// ---------------- GEMM1: qkv = x @ Wqkv^T, fused RoPE epilogue ----------------
// FAT-PHASE + multi-tile (r8, ~61 us, 835 TF). LDS-BW-bound at its structural
// floor (16 b128/32 MFMA; MfmaUtil 34% == LDS-pipe ratio). FROZEN.
#define QKV_NT 32
#define QBAR() do { __builtin_amdgcn_s_barrier(); __builtin_amdgcn_sched_barrier(0); } while (0)
#define WAITV(n) asm volatile("s_waitcnt vmcnt(" #n ")" ::: "memory")
#define LGKM0() do { asm volatile("s_waitcnt lgkmcnt(0)" ::: "memory"); \
                     __builtin_amdgcn_sched_barrier(0); } while (0)

__global__ __launch_bounds__(256, 2) void gemm_qkv(const bf16* __restrict__ A,
                                                   const bf16* __restrict__ W,
                                                   bf16* __restrict__ q_ws,
                                                   bf16* __restrict__ k_ws,
                                                   bf16* __restrict__ v_ws) {
  // elems: buf c at c*16384; slots: A-kk0 +0, A-kk1 +4096, B-kk0 +8192, B-kk1 +12288
  __shared__ bf16 smem[32768];   // 64 KiB
  const int tid = threadIdx.x;
  const int wave = tid >> 6, lane = tid & 63;
  const int wm = wave >> 1, wn = wave & 1;         // 2x2 waves, tile 64x64 each
  const int srow = tid >> 2;                       // staging row 0..63 (+64 second copy)
  const int swc = (((tid & 3) ^ ((tid >> 3) & 3)) * 8);  // src chunk involution
  const int fr = lane & 15, fq = lane >> 4;
  const int rdc = ((fq ^ ((fr >> 1) & 3)) * 8);    // swizzled read chunk

  const int b = blockIdx.x;
  const int nrep = (b < 256) ? 2 : 1;

  const bf16 *Asrc, *Bsrc;
  auto stage = [&](int t_, int bufe_) {            // 8 loads/thread
#pragma unroll
    for (int kk = 0; kk < 2; ++kk) {
      const int ko = t_ * 64 + kk * 32;
      async_copy16(Asrc + ko, &smem[bufe_ + kk * 4096 + wave * 512]);
      async_copy16(Asrc + (size_t)64 * DMODEL + ko,
                   &smem[bufe_ + kk * 4096 + 2048 + wave * 512]);
      async_copy16(Bsrc + ko, &smem[bufe_ + 8192 + kk * 4096 + wave * 512]);
      async_copy16(Bsrc + (size_t)64 * DMODEL + ko,
                   &smem[bufe_ + 8192 + kk * 4096 + 2048 + wave * 512]);
    }
  };

  const f32x4 zero = {0.f, 0.f, 0.f, 0.f};
  f32x4 acc[4][4];
  short8 a0[4], a1[4], b0[4], b1[4];

  for (int rep = 0; rep < nrep; ++rep) {
    const int tile = (rep == 0) ? b : (512 + b);
    const int m0 = (tile / 48) * 128, n0 = (tile % 48) * 128;
    Asrc = A + (size_t)(m0 + srow) * DMODEL + swc;
    Bsrc = W + (size_t)(n0 + srow) * DMODEL + swc;

#pragma unroll
    for (int i = 0; i < 4; ++i)
#pragma unroll
      for (int j = 0; j < 4; ++j) acc[i][j] = zero;

    if (rep) __syncthreads();   // prior tile's epilogue LDS reads done block-wide

    stage(0, 0);
    stage(1, 16384);
    WAITV(8);   // T0 landed (FIFO: also drains any leftover epilogue stores)
    QBAR();

#pragma unroll 2
    for (int t = 0; t < QKV_NT; ++t) {
      const int bc = (t & 1) * 16384;
#pragma unroll
      for (int mi = 0; mi < 4; ++mi) {
        const int ro = (wm * 64 + mi * 16 + fr) * 32 + rdc;
        a0[mi] = *(const short8*)&smem[bc + ro];
        a1[mi] = *(const short8*)&smem[bc + 4096 + ro];
      }
#pragma unroll
      for (int n = 0; n < 4; ++n) {
        const int ro = (wn * 64 + n * 16 + fr) * 32 + rdc;
        b0[n] = *(const short8*)&smem[bc + 8192 + ro];
        b1[n] = *(const short8*)&smem[bc + 12288 + ro];
      }
      LGKM0();                        // my frags in regs
      QBAR();                         // all waves done reading buf bc
      if (t + 2 < QKV_NT) stage(t + 2, bc);   // overwrite bc with T+2
      __builtin_amdgcn_s_setprio(1);
#pragma unroll
      for (int mi = 0; mi < 4; ++mi)
#pragma unroll
        for (int n = 0; n < 4; ++n)
          acc[mi][n] = mfma_bf16(a0[mi], b0[n], acc[mi][n]);
#pragma unroll
      for (int mi = 0; mi < 4; ++mi)
#pragma unroll
        for (int n = 0; n < 4; ++n)
          acc[mi][n] = mfma_bf16(a1[mi], b1[n], acc[mi][n]);
      __builtin_amdgcn_s_setprio(0);
      if (t + 2 < QKV_NT)      { WAITV(8); }  // T+1 landed; T+2 in flight
      else if (t + 1 < QKV_NT) { WAITV(0); }  // tail drain
      QBAR();
    }

    // ------------- epilogue: RoPE for Q/K, transpose-store for V -------------
    const int colb = n0 + wn * 64;
    const int sect = colb >> 11;        // 0=q, 1=k, 2=v (never mixed within a tile)
    const int h = (colb & 2047) >> 6;
    const int col = fr, rq = fq * 4;

    if (sect < 2) {
      bf16* dst = ((sect == 0) ? q_ws : k_ws) + (size_t)h * S_LEN * HDIM;
      bf16* rep_b = smem + wave * 1152;   // 16 rows x stride 72 (16B-aligned)
      const float qs = (sect == 0) ? Q_PRESCALE : 1.0f; // fold softmax scale into Q
      const float f0 = exp2f(-(float)col * ROPE_L2);
      const float f1 = exp2f(-(float)(16 + col) * ROPE_L2);
      __syncthreads();
      for (int m = 0; m < 4; ++m) {
        const int base_s = m0 + wm * 64 + m * 16;
#pragma unroll
        for (int jl = 0; jl < 2; ++jl) {
          const int dh = jl * 16 + col;
          const float fr_ = (jl == 0) ? f0 : f1;
#pragma unroll
          for (int r = 0; r < 4; ++r) {
            const int srw = base_s + rq + r;
            float sn, cs;
            __sincosf((float)srw * fr_, &sn, &cs);
            const float xl = acc[m][jl][r], xh = acc[m][jl + 2][r];
            rep_b[(rq + r) * 72 + dh]      = __float2bfloat16((xl * cs - xh * sn) * qs);
            rep_b[(rq + r) * 72 + dh + 32] = __float2bfloat16((xh * cs + xl * sn) * qs);
          }
        }
#pragma unroll
        for (int p = 0; p < 2; ++p) {
          const int rr = p * 8 + (lane >> 3), ch = lane & 7;
          const uint4 vv = *(const uint4*)&rep_b[rr * 72 + ch * 8];
          *(uint4*)&dst[(size_t)(base_s + rr) * HDIM + ch * 8] = vv;
        }
      }
    } else {
      // V stored transposed: [h][dh][s]
      bf16* dst = v_ws + (size_t)h * HDIM * S_LEN;
      for (int j = 0; j < 4; ++j) {
        const int dh = j * 16 + col;
        for (int m = 0; m < 4; ++m) {
          const int s0 = m0 + wm * 64 + m * 16 + rq;
          union { bf16 hx[4]; uint2 u; } vk;
#pragma unroll
          for (int r = 0; r < 4; ++r) vk.hx[r] = __float2bfloat16(acc[m][j][r]);
          *(uint2*)&dst[(size_t)dh * S_LEN + s0] = vk.u;
        }
      }
    }
  }
}

// ---------------- flash attention (causal) — k-split + 80 KiB LDS, (512,2) ----------------
// r9 k-split math + r10's LDS compaction (PL 36.9 -> 16 KiB via sequential-g
// and XOR bank swizzle; vf load after softmax) + the CORRECT launch bound:
// r10's (512,4) was interpreted as min 4 BLOCKS/CU -> 64-VGPR cap -> scratch
// spills (VGPR_Count=64, WRITE_SIZE 20 GB). (512,2) = min 2 blocks/CU ->
// 128-VGPR cap, which r9 proved this math fits without spills. LDS 80 KiB
// -> 2 blocks/CU, 4 waves/SIMD (r9 had 1 block/CU at 100 KiB).
__global__ __launch_bounds__(512, 2) void attn_kernel(const bf16* __restrict__ q_ws,
                                                      const bf16* __restrict__ k_ws,
                                                      const bf16* __restrict__ vt_ws,
                                                      bf16* __restrict__ attn_out) {
  const int bid = blockIdx.x;
  const int qt = 15 - (bid >> 5);      // heavy q-tiles first (LPT)
  const int h = bid & 31;

  const int tid = threadIdx.x, wave = tid >> 6, lane = tid & 63;
  const int wq = wave & 3, wk = wave >> 2;
  const int col = lane & 15, fq = lane >> 4;
  const int qbase = qt * 128 + wq * 32;

  // layout (bf16 elems): KS 0..16383 (2 bufs x 128x64), VS 16384..32767
  // (2 bufs x 64x128), PL 32768..40959 (8 waves x 16 rows x 64, XOR-swizzled)
  __shared__ __align__(16) bf16 smem[40960];   // 80 KiB
  bf16* KS = smem;
  bf16* VS = smem + 16384;
  bf16* pl = smem + 32768 + wave * 1024;
  const int plsw = (col & 7) << 3;             // per-lane row XOR key

  const bf16* qh = q_ws + (size_t)h * S_LEN * HDIM;
  const bf16* kh = k_ws + (size_t)h * S_LEN * HDIM;
  const bf16* vh = vt_ws + (size_t)h * HDIM * S_LEN;

  const int srow = lane >> 3;
  const int schunk = (lane & 7) ^ srow;          // K staging involution (key = krow&7)

  // stage superstep ss = tiles {2ss, 2ss+1}: 4 loads/thread
  auto stage = [&](int ss, int buf) {
    const int k0 = ss * 128;
#pragma unroll
    for (int j = 0; j < 2; ++j) {
      const int kr = j * 64 + wave * 8 + srow;
      async_copy16(kh + (size_t)(k0 + kr) * HDIM + schunk * 8,
                   &KS[buf * 8192 + (j * 64 + wave * 8) * 64]);
    }
#pragma unroll
    for (int j = 0; j < 2; ++j) {
      const int dh = j * 32 + wave * 4 + (lane >> 4);
      const int cg = (lane & 15) ^ (dh & 7);     // V staging involution (key = dh&7)
      async_copy16(vh + (size_t)dh * S_LEN + k0 + cg * 8,
                   &VS[buf * 8192 + (j * 32 + wave * 4) * 128]);
    }
  };

  short8 qf[2][2];
#pragma unroll
  for (int g = 0; g < 2; ++g)
#pragma unroll
    for (int ks = 0; ks < 2; ++ks)
      qf[g][ks] = *(const short8*)&qh[(size_t)(qbase + g * 16 + col) * HDIM +
                                      ks * 32 + fq * 8];

  const f32x4 zero = {0.f, 0.f, 0.f, 0.f};
  f32x4 o_acc[2][4];
#pragma unroll
  for (int g = 0; g < 2; ++g)
#pragma unroll
    for (int n = 0; n < 4; ++n) o_acc[g][n] = zero;
  float m_i[2] = {-1e9f, -1e9f}, l_i[2] = {0.f, 0.f};

  stage(0, 0);

  for (int ss = 0; ss <= qt; ++ss) {
    const int buf = ss & 1;
    __syncthreads();                    // staged loads landed (vmcnt drained)
    if (ss < qt) stage(ss + 1, buf ^ 1);

    const int k0 = ss * 128 + wk * 64;  // this group's tile

    short8 kf[8];
#pragma unroll
    for (int n = 0; n < 4; ++n) {
      const int r = wk * 64 + n * 16 + col;
#pragma unroll
      for (int ks = 0; ks < 2; ++ks)
        kf[n * 2 + ks] =
            *(const short8*)&KS[buf * 8192 + r * 64 + (((ks * 4 + fq) ^ (r & 7)) * 8)];
    }
    f32x4 s_acc[2][4];
#pragma unroll
    for (int g = 0; g < 2; ++g)
#pragma unroll
      for (int n = 0; n < 4; ++n) s_acc[g][n] = zero;
#pragma unroll
    for (int g = 0; g < 2; ++g)
#pragma unroll
      for (int n = 0; n < 4; ++n)
#pragma unroll
        for (int ks = 0; ks < 2; ++ks)
          s_acc[g][n] = mfma_bf16(kf[n * 2 + ks], qf[g][ks], s_acc[g][n]);

    if (k0 + 63 > qbase) {              // tile can cross diagonal (wave-uniform)
#pragma unroll
      for (int g = 0; g < 2; ++g) {
        const int qg = qbase + g * 16 + col;
#pragma unroll
        for (int n = 0; n < 4; ++n)
#pragma unroll
          for (int r = 0; r < 4; ++r)
            if (k0 + n * 16 + fq * 4 + r > qg) s_acc[g][n][r] = -1e30f;
      }
    }

    short8 pa[2][2];
#pragma unroll
    for (int g = 0; g < 2; ++g) {
      float vmax = -1e30f;
#pragma unroll
      for (int n = 0; n < 4; ++n)
#pragma unroll
        for (int r = 0; r < 4; ++r) vmax = fmaxf(vmax, s_acc[g][n][r]);
      vmax = fmaxf(vmax, __shfl_xor(vmax, 16, 64));
      vmax = fmaxf(vmax, __shfl_xor(vmax, 32, 64));

      // T13 defer-max (log2 domain)
      if (!__all(vmax - m_i[g] <= 8.0f)) {
        const float mnew = fmaxf(m_i[g], vmax);
        const float alpha = exp2f(m_i[g] - mnew);
        l_i[g] *= alpha;
#pragma unroll
        for (int n = 0; n < 4; ++n)
#pragma unroll
          for (int r = 0; r < 4; ++r) o_acc[g][n][r] *= alpha;
        m_i[g] = mnew;
      }

      float rs = 0.f;
#pragma unroll
      for (int n = 0; n < 4; ++n)
#pragma unroll
        for (int r = 0; r < 4; ++r) {
          const float p = exp2f(s_acc[g][n][r] - m_i[g]);
          s_acc[g][n][r] = p;
          rs += p;
        }
      rs += __shfl_xor(rs, 16, 64);
      rs += __shfl_xor(rs, 32, 64);
      l_i[g] += rs;

      // write this g's P rows into the 16-row swizzled buffer, read pa, then
      // g=1 reuses the same rows (wave-internal DS ordering via compiler deps)
#pragma unroll
      for (int n = 0; n < 4; ++n) {
        union { bf16 hx[4]; uint2 u; } pk;
#pragma unroll
        for (int r = 0; r < 4; ++r) pk.hx[r] = __float2bfloat16(s_acc[g][n][r]);
        *(uint2*)&pl[col * 64 + ((n * 16 + fq * 4) ^ plsw)] = pk.u;
      }
#pragma unroll
      for (int ks = 0; ks < 2; ++ks)
        pa[g][ks] = *(const short8*)&pl[col * 64 + ((ks * 32 + fq * 8) ^ plsw)];
    }

    short8 vf[8];
#pragma unroll
    for (int n = 0; n < 4; ++n) {
      const int dh = n * 16 + col;
#pragma unroll
      for (int ks = 0; ks < 2; ++ks)
        vf[n * 2 + ks] =
            *(const short8*)&VS[buf * 8192 + dh * 128 +
                                (((wk * 8 + ks * 4 + fq) ^ (dh & 7)) * 8)];
    }

#pragma unroll
    for (int g = 0; g < 2; ++g)
#pragma unroll
      for (int n = 0; n < 4; ++n)
#pragma unroll
        for (int ks = 0; ks < 2; ++ks)
          o_acc[g][n] = mfma_bf16(vf[n * 2 + ks], pa[g][ks], o_acc[g][n]);
  }

  // -------- flash-merge: group B (waves 4-7) hands off to group A (0-3) --------
  __syncthreads();
  float* fo = (float*)smem;                 // KS region: 4 x 64 x 32 floats = 32 KB
  float* fm = (float*)(smem + 16384);       // VS region: 4 x 64 x 4 floats
  if (wave >= 4) {
    const int off = ((wave - 4) * 64 + lane) * 32;
#pragma unroll
    for (int g = 0; g < 2; ++g)
#pragma unroll
      for (int n = 0; n < 4; ++n)
        *(f32x4*)&fo[off + (g * 4 + n) * 4] = o_acc[g][n];
    const int moff = ((wave - 4) * 64 + lane) * 4;
    fm[moff + 0] = m_i[0];
    fm[moff + 1] = l_i[0];
    fm[moff + 2] = m_i[1];
    fm[moff + 3] = l_i[1];
  }
  __syncthreads();
  if (wave < 4) {
    const int off = (wave * 64 + lane) * 32;
    const int moff = (wave * 64 + lane) * 4;
#pragma unroll
    for (int g = 0; g < 2; ++g) {
      const float mB = fm[moff + g * 2], lB = fm[moff + g * 2 + 1];
      const float m = fmaxf(m_i[g], mB);
      const float a = exp2f(m_i[g] - m), bsc = exp2f(mB - m);
      const float l = l_i[g] * a + lB * bsc;
      const float inv = 1.0f / l;
      const int qg = qbase + g * 16 + col;
#pragma unroll
      for (int n = 0; n < 4; ++n) {
        const f32x4 oB = *(const f32x4*)&fo[off + (g * 4 + n) * 4];
        union { bf16 hx[4]; uint2 u; } ok;
#pragma unroll
        for (int r = 0; r < 4; ++r)
          ok.hx[r] = __float2bfloat16((o_acc[g][n][r] * a + oB[r] * bsc) * inv);
        *(uint2*)&attn_out[(size_t)qg * DMODEL + h * HDIM + n * 16 + fq * 4] = ok.u;
      }
    }
  }
}

// ---------------- GEMM2: out = attn @ Wo^T, fused residual+gate ----------------
// FAT-PHASE (r8): 128x128 tile, grid 256 (1 block/CU), 512 thr / 8 waves,
// wave tile 64x32, BK=64 in one phase, 64 KiB dbuf, counted WAITV(4). FROZEN.
__global__ __launch_bounds__(512, 2) void gemm_out(const bf16* __restrict__ A,
                                                   const bf16* __restrict__ W,
                                                   const float* __restrict__ xres,
                                                   const float* __restrict__ gate,
                                                   float* __restrict__ out) {
  constexpr int K = DMODEL;
  constexpr int NT = K / 64;           // 32 fat K-steps
  // elems: buf c at c*16384; slots: A-kk0 +0, A-kk1 +4096, B-kk0 +8192, B-kk1 +12288
  __shared__ bf16 smem[32768];         // 64 KiB
  const int tid = threadIdx.x;
  const int wave = tid >> 6, lane = tid & 63;
  const int wm = wave >> 2, wn = wave & 3;   // wave tile 64(m) x 32(n)
  const int m0 = blockIdx.y * 128, n0 = blockIdx.x * 128;
  const int srow = tid >> 2;                 // staging row 0..127
  const int swc = (((tid & 3) ^ ((tid >> 3) & 3)) * 8);  // src chunk involution
  const int fr = lane & 15, fq = lane >> 4;
  const int rdc = ((fq ^ ((fr >> 1) & 3)) * 8);          // swizzled read chunk

  const bf16* Asrc = A + (size_t)(m0 + srow) * K + swc;
  const bf16* Bsrc = W + (size_t)(n0 + srow) * K + swc;

  auto stage = [&](int t_, int bufe_) {      // 4 loads/thread
#pragma unroll
    for (int kk = 0; kk < 2; ++kk) {
      const int ko = t_ * 64 + kk * 32;
      async_copy16(Asrc + ko, &smem[bufe_ + kk * 4096 + wave * 512]);
      async_copy16(Bsrc + ko, &smem[bufe_ + 8192 + kk * 4096 + wave * 512]);
    }
  };

  const f32x4 zero = {0.f, 0.f, 0.f, 0.f};
  f32x4 acc[4][2];
#pragma unroll
  for (int i = 0; i < 4; ++i)
#pragma unroll
    for (int j = 0; j < 2; ++j) acc[i][j] = zero;
  short8 a0[4], a1[4], b0[2], b1[2];

  stage(0, 0);
  stage(1, 16384);
  WAITV(4);       // T0 landed; T1 (4) in flight
  QBAR();

  for (int t = 0; t < NT; ++t) {
    const int bc = (t & 1) * 16384;
#pragma unroll
    for (int i = 0; i < 4; ++i) {
      const int ro = (wm * 64 + i * 16 + fr) * 32 + rdc;
      a0[i] = *(const short8*)&smem[bc + ro];
      a1[i] = *(const short8*)&smem[bc + 4096 + ro];
    }
#pragma unroll
    for (int j = 0; j < 2; ++j) {
      const int ro = (wn * 32 + j * 16 + fr) * 32 + rdc;
      b0[j] = *(const short8*)&smem[bc + 8192 + ro];
      b1[j] = *(const short8*)&smem[bc + 12288 + ro];
    }
    LGKM0();                           // my frags in regs
    QBAR();                            // all waves done reading buf bc
    if (t + 2 < NT) stage(t + 2, bc);  // overwrite bc with T+2
    __builtin_amdgcn_s_setprio(1);
#pragma unroll
    for (int i = 0; i < 4; ++i)
#pragma unroll
      for (int j = 0; j < 2; ++j)
        acc[i][j] = mfma_bf16(a0[i], b0[j], acc[i][j]);
#pragma unroll
    for (int i = 0; i < 4; ++i)
#pragma unroll
      for (int j = 0; j < 2; ++j)
        acc[i][j] = mfma_bf16(a1[i], b1[j], acc[i][j]);
    __builtin_amdgcn_s_setprio(0);
    if (t + 2 < NT)      { WAITV(4); } // T+1 landed; T+2 in flight
    else if (t + 1 < NT) { WAITV(0); } // tail drain
    QBAR();
  }

  const int col = fr, rq = fq * 4;
  for (int j = 0; j < 2; ++j) {
    const int cc = n0 + wn * 32 + j * 16 + col;
    const float g = gate[cc];
    for (int i = 0; i < 4; ++i) {
      const int base_row = m0 + wm * 64 + i * 16 + rq;
      for (int r = 0; r < 4; ++r) {
        const size_t idx = (size_t)(base_row + r) * DMODEL + cc;
        out[idx] = xres[idx] + g * acc[i][j][r];
      }
    }
  }
}

extern "C" void kernel_launch(void* const* d_in, const int* in_sizes, int n_in,
                              void* d_out, int out_size, void* d_ws, size_t ws_size,
                              hipStream_t stream) {
  const float* x    = (const float*)d_in[0];
  const float* Wqkv = (const float*)d_in[1];
  const float* Wo   = (const float*)d_in[2];
  const float* gate = (const float*)d_in[3];
  float* out = (float*)d_out;

  char* ws = (char*)d_ws;
  const size_t MB = 1024 * 1024;
  bf16* xb      = (bf16*)(ws);                 // 8 MB   (dead after gemm_qkv)
  bf16* wqkvb   = (bf16*)(ws + 8 * MB);        // 24 MB  (dead after gemm_qkv)
  bf16* wob     = (bf16*)(ws + 32 * MB);       // 8 MB
  bf16* q_ws    = (bf16*)(ws + 40 * MB);       // 8 MB  [h][s][dh] (prescaled by 0.125*log2e)
  bf16* k_ws    = (bf16*)(ws + 48 * MB);       // 8 MB  [h][s][dh]
  bf16* v_ws    = (bf16*)(ws + 56 * MB);       // 8 MB  [h][dh][s] (pre-transposed)
  bf16* attn_ws = (bf16*)(ws);                 // aliases xb

  cvt3_kernel<<<dim3(20480), 256, 0, stream>>>(x, xb, Wqkv, wqkvb, Wo, wob);

  gemm_qkv<<<dim3(512), 256, 0, stream>>>(xb, wqkvb, q_ws, k_ws, v_ws);
  attn_kernel<<<dim3(512), 512, 0, stream>>>(q_ws, k_ws, v_ws, attn_ws);
  gemm_out<<<dim3(DMODEL / 128, DMODEL / 128), 512, 0, stream>>>(attn_ws, wob, x, gate, out);
}

// Round 13
// 241.328 us; speedup vs baseline: 1.0109x; 1.0109x over previous
//
#include <hip/hip_runtime.h>
#include <hip/hip_bf16.h>
#include <cstdint>
#include <cstddef>

typedef __hip_bfloat16 bf16;
typedef short short8 __attribute__((ext_vector_type(8)));
typedef float f32x4 __attribute__((ext_vector_type(4)));

#define S_LEN 2048
#define DMODEL 2048
#define NQKV 6144
#define NHEADS 32
#define HDIM 64
// log2(10000)/32
#define ROPE_L2 0.4152410118609203f
// 0.125 * log2(e): folded into Q so attn softmax runs in exp2 domain
#define Q_PRESCALE 0.18033688011112042f

__device__ __forceinline__ void async_copy16(const bf16* g, bf16* l) {
  __builtin_amdgcn_global_load_lds(
      (const __attribute__((address_space(1))) void*)g,
      (__attribute__((address_space(3))) void*)l, 16, 0, 0);
}

__device__ __forceinline__ f32x4 mfma_bf16(short8 a, short8 b, f32x4 c) {
  return __builtin_amdgcn_mfma_f32_16x16x32_bf16(a, b, c, 0, 0, 0);
}

// ---------------- fused fp32 -> bf16 convert of x, Wqkv, Wo ----------------
__global__ __launch_bounds__(256) void cvt3_kernel(const float* __restrict__ sx,
                                                   bf16* __restrict__ dx,
                                                   const float* __restrict__ sw,
                                                   bf16* __restrict__ dw,
                                                   const float* __restrict__ so,
                                                   bf16* __restrict__ dov) {
  int i = blockIdx.x * 256 + threadIdx.x;
  const float* s;
  bf16* d;
  if (i < 1048576) {
    s = sx; d = dx;
  } else if (i < 4194304) {
    s = sw; d = dw; i -= 1048576;
  } else {
    s = so; d = dov; i -= 4194304;
  }
  const float4 v = ((const float4*)s)[i];
  union { bf16 h[4]; ushort4 u; } tmp;
  tmp.h[0] = __float2bfloat16(v.x);
  tmp.h[1] = __float2bfloat16(v.y);
  tmp.h[2] = __float2bfloat16(v.z);
  tmp.h[3] = __float2bfloat16(v.w);
  ((ushort4*)d)[i] = tmp.u;
}

// ---------------- GEMM1: qkv = x @ Wqkv^T, fused RoPE epilogue ----------------
// FAT-PHASE + multi-tile (r8, ~61 us, 835 TF). LDS-BW-bound at its structural
// floor (16 b128/32 MFMA; MfmaUtil 34% == LDS-pipe ratio). FINAL.
#define QKV_NT 32
#define QBAR() do { __builtin_amdgcn_s_barrier(); __builtin_amdgcn_sched_barrier(0); } while (0)
#define WAITV(n) asm volatile("s_waitcnt vmcnt(" #n ")" ::: "memory")
#define LGKM0() do { asm volatile("s_waitcnt lgkmcnt(0)" ::: "memory"); \
                     __builtin_amdgcn_sched_barrier(0); } while (0)

__global__ __launch_bounds__(256, 2) void gemm_qkv(const bf16* __restrict__ A,
                                                   const bf16* __restrict__ W,
                                                   bf16* __restrict__ q_ws,
                                                   bf16* __restrict__ k_ws,
                                                   bf16* __restrict__ v_ws) {
  // elems: buf c at c*16384; slots: A-kk0 +0, A-kk1 +4096, B-kk0 +8192, B-kk1 +12288
  __shared__ bf16 smem[32768];   // 64 KiB
  const int tid = threadIdx.x;
  const int wave = tid >> 6, lane = tid & 63;
  const int wm = wave >> 1, wn = wave & 1;         // 2x2 waves, tile 64x64 each
  const int srow = tid >> 2;                       // staging row 0..63 (+64 second copy)
  const int swc = (((tid & 3) ^ ((tid >> 3) & 3)) * 8);  // src chunk involution
  const int fr = lane & 15, fq = lane >> 4;
  const int rdc = ((fq ^ ((fr >> 1) & 3)) * 8);    // swizzled read chunk

  const int b = blockIdx.x;
  const int nrep = (b < 256) ? 2 : 1;

  const bf16 *Asrc, *Bsrc;
  auto stage = [&](int t_, int bufe_) {            // 8 loads/thread
#pragma unroll
    for (int kk = 0; kk < 2; ++kk) {
      const int ko = t_ * 64 + kk * 32;
      async_copy16(Asrc + ko, &smem[bufe_ + kk * 4096 + wave * 512]);
      async_copy16(Asrc + (size_t)64 * DMODEL + ko,
                   &smem[bufe_ + kk * 4096 + 2048 + wave * 512]);
      async_copy16(Bsrc + ko, &smem[bufe_ + 8192 + kk * 4096 + wave * 512]);
      async_copy16(Bsrc + (size_t)64 * DMODEL + ko,
                   &smem[bufe_ + 8192 + kk * 4096 + 2048 + wave * 512]);
    }
  };

  const f32x4 zero = {0.f, 0.f, 0.f, 0.f};
  f32x4 acc[4][4];
  short8 a0[4], a1[4], b0[4], b1[4];

  for (int rep = 0; rep < nrep; ++rep) {
    const int tile = (rep == 0) ? b : (512 + b);
    const int m0 = (tile / 48) * 128, n0 = (tile % 48) * 128;
    Asrc = A + (size_t)(m0 + srow) * DMODEL + swc;
    Bsrc = W + (size_t)(n0 + srow) * DMODEL + swc;

#pragma unroll
    for (int i = 0; i < 4; ++i)
#pragma unroll
      for (int j = 0; j < 4; ++j) acc[i][j] = zero;

    if (rep) __syncthreads();   // prior tile's epilogue LDS reads done block-wide

    stage(0, 0);
    stage(1, 16384);
    WAITV(8);   // T0 landed (FIFO: also drains any leftover epilogue stores)
    QBAR();

#pragma unroll 2
    for (int t = 0; t < QKV_NT; ++t) {
      const int bc = (t & 1) * 16384;
#pragma unroll
      for (int mi = 0; mi < 4; ++mi) {
        const int ro = (wm * 64 + mi * 16 + fr) * 32 + rdc;
        a0[mi] = *(const short8*)&smem[bc + ro];
        a1[mi] = *(const short8*)&smem[bc + 4096 + ro];
      }
#pragma unroll
      for (int n = 0; n < 4; ++n) {
        const int ro = (wn * 64 + n * 16 + fr) * 32 + rdc;
        b0[n] = *(const short8*)&smem[bc + 8192 + ro];
        b1[n] = *(const short8*)&smem[bc + 12288 + ro];
      }
      LGKM0();                        // my frags in regs
      QBAR();                         // all waves done reading buf bc
      if (t + 2 < QKV_NT) stage(t + 2, bc);   // overwrite bc with T+2
      __builtin_amdgcn_s_setprio(1);
#pragma unroll
      for (int mi = 0; mi < 4; ++mi)
#pragma unroll
        for (int n = 0; n < 4; ++n)
          acc[mi][n] = mfma_bf16(a0[mi], b0[n], acc[mi][n]);
#pragma unroll
      for (int mi = 0; mi < 4; ++mi)
#pragma unroll
        for (int n = 0; n < 4; ++n)
          acc[mi][n] = mfma_bf16(a1[mi], b1[n], acc[mi][n]);
      __builtin_amdgcn_s_setprio(0);
      if (t + 2 < QKV_NT)      { WAITV(8); }  // T+1 landed; T+2 in flight
      else if (t + 1 < QKV_NT) { WAITV(0); }  // tail drain
      QBAR();
    }

    // ------------- epilogue: RoPE for Q/K, transpose-store for V -------------
    const int colb = n0 + wn * 64;
    const int sect = colb >> 11;        // 0=q, 1=k, 2=v (never mixed within a tile)
    const int h = (colb & 2047) >> 6;
    const int col = fr, rq = fq * 4;

    if (sect < 2) {
      bf16* dst = ((sect == 0) ? q_ws : k_ws) + (size_t)h * S_LEN * HDIM;
      bf16* rep_b = smem + wave * 1152;   // 16 rows x stride 72 (16B-aligned)
      const float qs = (sect == 0) ? Q_PRESCALE : 1.0f; // fold softmax scale into Q
      const float f0 = exp2f(-(float)col * ROPE_L2);
      const float f1 = exp2f(-(float)(16 + col) * ROPE_L2);
      __syncthreads();
      for (int m = 0; m < 4; ++m) {
        const int base_s = m0 + wm * 64 + m * 16;
#pragma unroll
        for (int jl = 0; jl < 2; ++jl) {
          const int dh = jl * 16 + col;
          const float fr_ = (jl == 0) ? f0 : f1;
#pragma unroll
          for (int r = 0; r < 4; ++r) {
            const int srw = base_s + rq + r;
            float sn, cs;
            __sincosf((float)srw * fr_, &sn, &cs);
            const float xl = acc[m][jl][r], xh = acc[m][jl + 2][r];
            rep_b[(rq + r) * 72 + dh]      = __float2bfloat16((xl * cs - xh * sn) * qs);
            rep_b[(rq + r) * 72 + dh + 32] = __float2bfloat16((xh * cs + xl * sn) * qs);
          }
        }
#pragma unroll
        for (int p = 0; p < 2; ++p) {
          const int rr = p * 8 + (lane >> 3), ch = lane & 7;
          const uint4 vv = *(const uint4*)&rep_b[rr * 72 + ch * 8];
          *(uint4*)&dst[(size_t)(base_s + rr) * HDIM + ch * 8] = vv;
        }
      }
    } else {
      // V stored transposed: [h][dh][s]
      bf16* dst = v_ws + (size_t)h * HDIM * S_LEN;
      for (int j = 0; j < 4; ++j) {
        const int dh = j * 16 + col;
        for (int m = 0; m < 4; ++m) {
          const int s0 = m0 + wm * 64 + m * 16 + rq;
          union { bf16 hx[4]; uint2 u; } vk;
#pragma unroll
          for (int r = 0; r < 4; ++r) vk.hx[r] = __float2bfloat16(acc[m][j][r]);
          *(uint2*)&dst[(size_t)dh * S_LEN + s0] = vk.u;
        }
      }
    }
  }
}

// ---------------- flash attention (causal) — k-split: 4 q-slices x 2 k-groups ----------------
// FINAL = r9/r11 measured-best (total 242.0/242.4): waves (wq=wave&3,
// wk=wave>>2); wave owns 32 q-rows, processes only its k-group's 64-row tile.
// Per superstep the block stages TWO k-tiles (128 K-rows, 64x128 V).
// Reads/MFMA 0.625; supersteps halved vs r7. One flash-merge per block.
// grid 512 LPT, 100 KB LDS -> 1 block/CU, 2 waves/SIMD, (512,2) = 128-VGPR
// cap (no spills; r10 proved (512,4) -> 64-reg cap -> 20 GB scratch, +14 us;
// r12 proved 80KB/2-blocks-CU occupancy gives null — barrier-locked blocks
// just interleave stalls).
__global__ __launch_bounds__(512, 2) void attn_kernel(const bf16* __restrict__ q_ws,
                                                      const bf16* __restrict__ k_ws,
                                                      const bf16* __restrict__ vt_ws,
                                                      bf16* __restrict__ attn_out) {
  const int bid = blockIdx.x;
  const int qt = 15 - (bid >> 5);      // heavy q-tiles first (LPT)
  const int h = bid & 31;

  const int tid = threadIdx.x, wave = tid >> 6, lane = tid & 63;
  const int wq = wave & 3, wk = wave >> 2;
  const int col = lane & 15, fq = lane >> 4;
  const int qbase = qt * 128 + wq * 32;

  // layout (bf16 elems): KS 0..16383 (2 bufs x 128x64), VS 16384..32767
  // (2 bufs x 64x128), PL 32768..51199 (8 waves x 32x72)
  __shared__ __align__(16) bf16 smem[51200];   // 100 KiB
  bf16* KS = smem;
  bf16* VS = smem + 16384;
  bf16* pl = smem + 32768 + wave * 2304;

  const bf16* qh = q_ws + (size_t)h * S_LEN * HDIM;
  const bf16* kh = k_ws + (size_t)h * S_LEN * HDIM;
  const bf16* vh = vt_ws + (size_t)h * HDIM * S_LEN;

  const int srow = lane >> 3;
  const int schunk = (lane & 7) ^ srow;          // K staging involution (key = krow&7)

  // stage superstep ss = tiles {2ss, 2ss+1}: 4 loads/thread
  auto stage = [&](int ss, int buf) {
    const int k0 = ss * 128;
#pragma unroll
    for (int j = 0; j < 2; ++j) {
      const int kr = j * 64 + wave * 8 + srow;
      async_copy16(kh + (size_t)(k0 + kr) * HDIM + schunk * 8,
                   &KS[buf * 8192 + (j * 64 + wave * 8) * 64]);
    }
#pragma unroll
    for (int j = 0; j < 2; ++j) {
      const int dh = j * 32 + wave * 4 + (lane >> 4);
      const int cg = (lane & 15) ^ (dh & 7);     // V staging involution (key = dh&7)
      async_copy16(vh + (size_t)dh * S_LEN + k0 + cg * 8,
                   &VS[buf * 8192 + (j * 32 + wave * 4) * 128]);
    }
  };

  short8 qf[2][2];
#pragma unroll
  for (int g = 0; g < 2; ++g)
#pragma unroll
    for (int ks = 0; ks < 2; ++ks)
      qf[g][ks] = *(const short8*)&qh[(size_t)(qbase + g * 16 + col) * HDIM +
                                      ks * 32 + fq * 8];

  const f32x4 zero = {0.f, 0.f, 0.f, 0.f};
  f32x4 o_acc[2][4];
#pragma unroll
  for (int g = 0; g < 2; ++g)
#pragma unroll
    for (int n = 0; n < 4; ++n) o_acc[g][n] = zero;
  float m_i[2] = {-1e9f, -1e9f}, l_i[2] = {0.f, 0.f};

  stage(0, 0);

  for (int ss = 0; ss <= qt; ++ss) {
    const int buf = ss & 1;
    __syncthreads();                    // staged loads landed (vmcnt drained)
    if (ss < qt) stage(ss + 1, buf ^ 1);

    const int k0 = ss * 128 + wk * 64;  // this group's tile

    short8 kf[8];
#pragma unroll
    for (int n = 0; n < 4; ++n) {
      const int r = wk * 64 + n * 16 + col;
#pragma unroll
      for (int ks = 0; ks < 2; ++ks)
        kf[n * 2 + ks] =
            *(const short8*)&KS[buf * 8192 + r * 64 + (((ks * 4 + fq) ^ (r & 7)) * 8)];
    }
    f32x4 s_acc[2][4];
#pragma unroll
    for (int g = 0; g < 2; ++g)
#pragma unroll
      for (int n = 0; n < 4; ++n) s_acc[g][n] = zero;
#pragma unroll
    for (int g = 0; g < 2; ++g)
#pragma unroll
      for (int n = 0; n < 4; ++n)
#pragma unroll
        for (int ks = 0; ks < 2; ++ks)
          s_acc[g][n] = mfma_bf16(kf[n * 2 + ks], qf[g][ks], s_acc[g][n]);

    short8 vf[8];
#pragma unroll
    for (int n = 0; n < 4; ++n) {
      const int dh = n * 16 + col;
#pragma unroll
      for (int ks = 0; ks < 2; ++ks)
        vf[n * 2 + ks] =
            *(const short8*)&VS[buf * 8192 + dh * 128 +
                                (((wk * 8 + ks * 4 + fq) ^ (dh & 7)) * 8)];
    }

    if (k0 + 63 > qbase) {              // tile can cross diagonal (wave-uniform)
#pragma unroll
      for (int g = 0; g < 2; ++g) {
        const int qg = qbase + g * 16 + col;
#pragma unroll
        for (int n = 0; n < 4; ++n)
#pragma unroll
          for (int r = 0; r < 4; ++r)
            if (k0 + n * 16 + fq * 4 + r > qg) s_acc[g][n][r] = -1e30f;
      }
    }

#pragma unroll
    for (int g = 0; g < 2; ++g) {
      float vmax = -1e30f;
#pragma unroll
      for (int n = 0; n < 4; ++n)
#pragma unroll
        for (int r = 0; r < 4; ++r) vmax = fmaxf(vmax, s_acc[g][n][r]);
      vmax = fmaxf(vmax, __shfl_xor(vmax, 16, 64));
      vmax = fmaxf(vmax, __shfl_xor(vmax, 32, 64));

      // T13 defer-max (log2 domain)
      if (!__all(vmax - m_i[g] <= 8.0f)) {
        const float mnew = fmaxf(m_i[g], vmax);
        const float alpha = exp2f(m_i[g] - mnew);
        l_i[g] *= alpha;
#pragma unroll
        for (int n = 0; n < 4; ++n)
#pragma unroll
          for (int r = 0; r < 4; ++r) o_acc[g][n][r] *= alpha;
        m_i[g] = mnew;
      }

      float rs = 0.f;
#pragma unroll
      for (int n = 0; n < 4; ++n)
#pragma unroll
        for (int r = 0; r < 4; ++r) {
          const float p = exp2f(s_acc[g][n][r] - m_i[g]);
          s_acc[g][n][r] = p;
          rs += p;
        }
      rs += __shfl_xor(rs, 16, 64);
      rs += __shfl_xor(rs, 32, 64);
      l_i[g] += rs;

#pragma unroll
      for (int n = 0; n < 4; ++n) {
        union { bf16 hx[4]; uint2 u; } pk;
#pragma unroll
        for (int r = 0; r < 4; ++r) pk.hx[r] = __float2bfloat16(s_acc[g][n][r]);
        *(uint2*)&pl[(g * 16 + col) * 72 + n * 16 + fq * 4] = pk.u;
      }
    }

    short8 pa[2][2];
#pragma unroll
    for (int g = 0; g < 2; ++g)
#pragma unroll
      for (int ks = 0; ks < 2; ++ks)
        pa[g][ks] = *(const short8*)&pl[(g * 16 + col) * 72 + ks * 32 + fq * 8];

#pragma unroll
    for (int g = 0; g < 2; ++g)
#pragma unroll
      for (int n = 0; n < 4; ++n)
#pragma unroll
        for (int ks = 0; ks < 2; ++ks)
          o_acc[g][n] = mfma_bf16(vf[n * 2 + ks], pa[g][ks], o_acc[g][n]);
  }

  // -------- flash-merge: group B (waves 4-7) hands off to group A (0-3) --------
  __syncthreads();
  float* fo = (float*)smem;                 // KS region: 4 x 64 x 32 floats = 32 KB
  float* fm = (float*)(smem + 16384);       // VS region: 4 x 64 x 4 floats
  if (wave >= 4) {
    const int off = ((wave - 4) * 64 + lane) * 32;
#pragma unroll
    for (int g = 0; g < 2; ++g)
#pragma unroll
      for (int n = 0; n < 4; ++n)
        *(f32x4*)&fo[off + (g * 4 + n) * 4] = o_acc[g][n];
    const int moff = ((wave - 4) * 64 + lane) * 4;
    fm[moff + 0] = m_i[0];
    fm[moff + 1] = l_i[0];
    fm[moff + 2] = m_i[1];
    fm[moff + 3] = l_i[1];
  }
  __syncthreads();
  if (wave < 4) {
    const int off = (wave * 64 + lane) * 32;
    const int moff = (wave * 64 + lane) * 4;
#pragma unroll
    for (int g = 0; g < 2; ++g) {
      const float mB = fm[moff + g * 2], lB = fm[moff + g * 2 + 1];
      const float m = fmaxf(m_i[g], mB);
      const float a = exp2f(m_i[g] - m), bsc = exp2f(mB - m);
      const float l = l_i[g] * a + lB * bsc;
      const float inv = 1.0f / l;
      const int qg = qbase + g * 16 + col;
#pragma unroll
      for (int n = 0; n < 4; ++n) {
        const f32x4 oB = *(const f32x4*)&fo[off + (g * 4 + n) * 4];
        union { bf16 hx[4]; uint2 u; } ok;
#pragma unroll
        for (int r = 0; r < 4; ++r)
          ok.hx[r] = __float2bfloat16((o_acc[g][n][r] * a + oB[r] * bsc) * inv);
        *(uint2*)&attn_out[(size_t)qg * DMODEL + h * HDIM + n * 16 + fq * 4] = ok.u;
      }
    }
  }
}

// ---------------- GEMM2: out = attn @ Wo^T, fused residual+gate ----------------
// FAT-PHASE (r8): 128x128 tile, grid 256 (1 block/CU), 512 thr / 8 waves,
// wave tile 64x32, BK=64 in one phase, 64 KiB dbuf, counted WAITV(4). FINAL.
__global__ __launch_bounds__(512, 2) void gemm_out(const bf16* __restrict__ A,
                                                   const bf16* __restrict__ W,
                                                   const float* __restrict__ xres,
                                                   const float* __restrict__ gate,
                                                   float* __restrict__ out) {
  constexpr int K = DMODEL;
  constexpr int NT = K / 64;           // 32 fat K-steps
  // elems: buf c at c*16384; slots: A-kk0 +0, A-kk1 +4096, B-kk0 +8192, B-kk1 +12288
  __shared__ bf16 smem[32768];         // 64 KiB
  const int tid = threadIdx.x;
  const int wave = tid >> 6, lane = tid & 63;
  const int wm = wave >> 2, wn = wave & 3;   // wave tile 64(m) x 32(n)
  const int m0 = blockIdx.y * 128, n0 = blockIdx.x * 128;
  const int srow = tid >> 2;                 // staging row 0..127
  const int swc = (((tid & 3) ^ ((tid >> 3) & 3)) * 8);  // src chunk involution
  const int fr = lane & 15, fq = lane >> 4;
  const int rdc = ((fq ^ ((fr >> 1) & 3)) * 8);          // swizzled read chunk

  const bf16* Asrc = A + (size_t)(m0 + srow) * K + swc;
  const bf16* Bsrc = W + (size_t)(n0 + srow) * K + swc;

  auto stage = [&](int t_, int bufe_) {      // 4 loads/thread
#pragma unroll
    for (int kk = 0; kk < 2; ++kk) {
      const int ko = t_ * 64 + kk * 32;
      async_copy16(Asrc + ko, &smem[bufe_ + kk * 4096 + wave * 512]);
      async_copy16(Bsrc + ko, &smem[bufe_ + 8192 + kk * 4096 + wave * 512]);
    }
  };

  const f32x4 zero = {0.f, 0.f, 0.f, 0.f};
  f32x4 acc[4][2];
#pragma unroll
  for (int i = 0; i < 4; ++i)
#pragma unroll
    for (int j = 0; j < 2; ++j) acc[i][j] = zero;
  short8 a0[4], a1[4], b0[2], b1[2];

  stage(0, 0);
  stage(1, 16384);
  WAITV(4);       // T0 landed; T1 (4) in flight
  QBAR();

  for (int t = 0; t < NT; ++t) {
    const int bc = (t & 1) * 16384;
#pragma unroll
    for (int i = 0; i < 4; ++i) {
      const int ro = (wm * 64 + i * 16 + fr) * 32 + rdc;
      a0[i] = *(const short8*)&smem[bc + ro];
      a1[i] = *(const short8*)&smem[bc + 4096 + ro];
    }
#pragma unroll
    for (int j = 0; j < 2; ++j) {
      const int ro = (wn * 32 + j * 16 + fr) * 32 + rdc;
      b0[j] = *(const short8*)&smem[bc + 8192 + ro];
      b1[j] = *(const short8*)&smem[bc + 12288 + ro];
    }
    LGKM0();                           // my frags in regs
    QBAR();                            // all waves done reading buf bc
    if (t + 2 < NT) stage(t + 2, bc);  // overwrite bc with T+2
    __builtin_amdgcn_s_setprio(1);
#pragma unroll
    for (int i = 0; i < 4; ++i)
#pragma unroll
      for (int j = 0; j < 2; ++j)
        acc[i][j] = mfma_bf16(a0[i], b0[j], acc[i][j]);
#pragma unroll
    for (int i = 0; i < 4; ++i)
#pragma unroll
      for (int j = 0; j < 2; ++j)
        acc[i][j] = mfma_bf16(a1[i], b1[j], acc[i][j]);
    __builtin_amdgcn_s_setprio(0);
    if (t + 2 < NT)      { WAITV(4); } // T+1 landed; T+2 in flight
    else if (t + 1 < NT) { WAITV(0); } // tail drain
    QBAR();
  }

  const int col = fr, rq = fq * 4;
  for (int j = 0; j < 2; ++j) {
    const int cc = n0 + wn * 32 + j * 16 + col;
    const float g = gate[cc];
    for (int i = 0; i < 4; ++i) {
      const int base_row = m0 + wm * 64 + i * 16 + rq;
      for (int r = 0; r < 4; ++r) {
        const size_t idx = (size_t)(base_row + r) * DMODEL + cc;
        out[idx] = xres[idx] + g * acc[i][j][r];
      }
    }
  }
}

extern "C" void kernel_launch(void* const* d_in, const int* in_sizes, int n_in,
                              void* d_out, int out_size, void* d_ws, size_t ws_size,
                              hipStream_t stream) {
  const float* x    = (const float*)d_in[0];
  const float* Wqkv = (const float*)d_in[1];
  const float* Wo   = (const float*)d_in[2];
  const float* gate = (const float*)d_in[3];
  float* out = (float*)d_out;

  char* ws = (char*)d_ws;
  const size_t MB = 1024 * 1024;
  bf16* xb      = (bf16*)(ws);                 // 8 MB   (dead after gemm_qkv)
  bf16* wqkvb   = (bf16*)(ws + 8 * MB);        // 24 MB  (dead after gemm_qkv)
  bf16* wob     = (bf16*)(ws + 32 * MB);       // 8 MB
  bf16* q_ws    = (bf16*)(ws + 40 * MB);       // 8 MB  [h][s][dh] (prescaled by 0.125*log2e)
  bf16* k_ws    = (bf16*)(ws + 48 * MB);       // 8 MB  [h][s][dh]
  bf16* v_ws    = (bf16*)(ws + 56 * MB);       // 8 MB  [h][dh][s] (pre-transposed)
  bf16* attn_ws = (bf16*)(ws);                 // aliases xb

  cvt3_kernel<<<dim3(20480), 256, 0, stream>>>(x, xb, Wqkv, wqkvb, Wo, wob);

  gemm_qkv<<<dim3(512), 256, 0, stream>>>(xb, wqkvb, q_ws, k_ws, v_ws);
  attn_kernel<<<dim3(512), 512, 0, stream>>>(q_ws, k_ws, v_ws, attn_ws);
  gemm_out<<<dim3(DMODEL / 128, DMODEL / 128), 512, 0, stream>>>(attn_ws, wob, x, gate, out);
}